// Round 6
// baseline (110.554 us; speedup 1.0000x reference)
//
#include <hip/hip_runtime.h>

#define BLOCK 8
#define NGRID 512

// ---------------------------------------------------------------------------
// Compile-time replication of
//   np.random.RandomState(0).choice(np.array([1.0,3.0],f32), size=(512,8))
// (MT19937 legacy scalar seeding, one 32-bit draw per value, value = draw&1).
// Bit i of pattern byte = element i: g[i] = bit ? 3.0f : 1.0f.
// Dedup (first occurrence) is argmax-neutral. kenc = 255 - dedup_index, so
// "ties -> max kenc" == numpy first-max.
// ---------------------------------------------------------------------------
struct Base {
  bool exists[256];
  unsigned char kenc[256];
  unsigned char kpat[256];  // kenc -> pattern byte
  int nd;
};

constexpr int popcount8c(int v) {
  int p = 0;
  for (int i = 0; i < 8; ++i) p += (v >> i) & 1;
  return p;
}

constexpr Base make_base() {
  Base t{};
  // --- MT19937, numpy legacy scalar seed 0 ---
  unsigned mt[624] = {};
  {
    unsigned s = 0u;
    for (int i = 0; i < 624; ++i) {
      mt[i] = s;
      s = 1812433253u * (s ^ (s >> 30)) + (unsigned)(i + 1);
    }
  }
  int pos = 624;
  int nd = 0;
  for (int j = 0; j < NGRID; ++j) {
    unsigned char b = 0;
    for (int i = 0; i < BLOCK; ++i) {
      if (pos == 624) {
        for (int k = 0; k < 624; ++k) {
          int k1 = (k + 1 < 624) ? k + 1 : 0;
          int k397 = (k + 397 < 624) ? k + 397 : k + 397 - 624;
          unsigned y = (mt[k] & 0x80000000u) | (mt[k1] & 0x7fffffffu);
          unsigned v = mt[k397] ^ (y >> 1);
          if (y & 1u) v ^= 0x9908b0dfu;
          mt[k] = v;
        }
        pos = 0;
      }
      unsigned y = mt[pos++];
      y ^= y >> 11;
      y ^= (y << 7) & 0x9d2c5680u;
      y ^= (y << 15) & 0xefc60000u;
      y ^= y >> 18;
      if (y & 1u) b |= (unsigned char)(1u << i);
    }
    if (!t.exists[b]) {
      t.exists[b] = true;
      t.kenc[b] = (unsigned char)(255 - nd);
      t.kpat[255 - nd] = b;
      ++nd;
    }
  }
  t.nd = nd;
  return t;
}

constexpr Base BS = make_base();

// epilogue gather table: kenc -> pattern byte
struct Pat { unsigned char p[256]; };
constexpr Pat make_pat() {
  Pat t{};
  for (int i = 0; i < 256; ++i) t.p[i] = BS.kpat[i];
  return t;
}
__device__ __constant__ Pat GP = make_pat();

// ---------------------------------------------------------------------------
// Chunk table (identical values to the proven R3/R4/R5 table, absmax
// 0.0078125): 32 chunks = the 32 low-5-bit prefix families (<= 8 members).
// Per chunk (48 dwords):
//   [0..4]   prefix coefs c_l (levels 0..4), f32 bits, c in {1.0, 3.0}
//   [5..28]  member coefs: m=0..7, levels 5..7 -> v[5 + 3m + (l-5)]
//   [29..44] member score consts: {negnf, rcf} per member (pads: {0, -1})
//   [45,46]  klut lo/hi: kenc byte per member slot
//   [47]     pad
// Members sorted by kenc ASCENDING (pads kenc=0 first) so the fixed-order
// eq-scan "last equal wins" == max kenc == numpy min-k tie-break.
// Bit-exactness argument unchanged from R3 (fma(a,1.0,s)==fl(a+s); uniform
// Markstein == 1-op path for pow2 norms; pads score -2*dd <= -0.0 never win).
// ---------------------------------------------------------------------------
struct CTab { unsigned v[32 * 48]; };

constexpr unsigned fb(float f) { return __builtin_bit_cast(unsigned, f); }

constexpr CTab make_ctab() {
  CTab t{};
  for (int P = 0; P < 32; ++P) {
    const int base = P * 48;
    for (int l = 0; l < 5; ++l)
      t.v[base + l] = fb(((P >> l) & 1) ? 3.0f : 1.0f);
    // gather family members (high 3 bits free)
    unsigned char mp[8] = {};
    int mk[8] = {};
    bool pf[8] = {};
    int n = 0;
    for (int hi = 0; hi < 8; ++hi) {
      int pat = P | (hi << 5);
      if (BS.exists[pat]) { mp[n] = (unsigned char)pat; mk[n] = BS.kenc[pat]; pf[n] = false; ++n; }
    }
    for (int i = n; i < 8; ++i) { mp[i] = (unsigned char)P; mk[i] = 0; pf[i] = true; }
    // insertion sort by kenc ascending (parallel arrays)
    for (int i = 1; i < 8; ++i) {
      int ki = mk[i]; unsigned char pi = mp[i]; bool fi = pf[i];
      int p = i - 1;
      while (p >= 0 && mk[p] > ki) {
        mk[p + 1] = mk[p]; mp[p + 1] = mp[p]; pf[p + 1] = pf[p]; --p;
      }
      mk[p + 1] = ki; mp[p + 1] = pi; pf[p + 1] = fi;
    }
    for (int m = 0; m < 8; ++m) {
      for (int dl = 0; dl < 3; ++dl)
        t.v[base + 5 + 3 * m + dl] = fb(((mp[m] >> (5 + dl)) & 1) ? 3.0f : 1.0f);
      float negnf = 0.0f, rcf = -1.0f;
      if (!pf[m]) {
        const int pc = popcount8c(mp[m]);
        const float nf = (float)(8 * (1 + pc));
        negnf = -nf;
        rcf = 1.0f / nf;  // RN reciprocal at compile time (same as before)
      }
      t.v[base + 29 + 2 * m] = fb(negnf);
      t.v[base + 30 + 2 * m] = fb(rcf);
    }
    unsigned lo = 0, hi2 = 0;
    for (int m = 0; m < 4; ++m) lo |= (unsigned)mk[m] << (8 * m);
    for (int m = 4; m < 8; ++m) hi2 |= (unsigned)mk[m] << (8 * (m - 4));
    t.v[base + 45] = lo;
    t.v[base + 46] = hi2;
    t.v[base + 47] = 0u;
  }
  return t;
}

__device__ __constant__ CTab CT = make_ctab();

// One block's chunk step from a register-resident table copy tb[48] (values
// bit-identical to the R5 kernel; transport does not affect rounding).
__device__ __forceinline__ void chunk_step(const float (&tb)[48],
                                           const float (&a)[BLOCK],
                                           float& gb, int& gk) {
  // shared low-5-bit prefix chain (levels 0..4)
  float pre = 0.0f;
#pragma unroll
  for (int l = 0; l < 5; ++l)
    pre = __builtin_fmaf(a[l], tb[l], pre);

  // 8 members: 3-fma suffix chain + dd + uniform Markstein score
  float sc[8];
#pragma unroll
  for (int m = 0; m < 8; ++m) {
    float d = pre;
    d = __builtin_fmaf(a[5], tb[5 + 3 * m + 0], d);
    d = __builtin_fmaf(a[6], tb[5 + 3 * m + 1], d);
    d = __builtin_fmaf(a[7], tb[5 + 3 * m + 2], d);
    float dd = d * d;
    float rcf = tb[30 + 2 * m];
    float q0 = dd * rcf;
    float r = __builtin_fmaf(tb[29 + 2 * m], q0, dd);
    sc[m] = __builtin_fmaf(r, rcf, q0);
  }

  float cm = __builtin_fmaxf(
      __builtin_fmaxf(__builtin_fmaxf(sc[0], sc[1]), __builtin_fmaxf(sc[2], sc[3])),
      __builtin_fmaxf(__builtin_fmaxf(sc[4], sc[5]), __builtin_fmaxf(sc[6], sc[7])));

  int ck = 0;
#pragma unroll
  for (int m = 0; m < 8; ++m)  // kenc ascending: last equal = max kenc = min k
    ck = (sc[m] == cm) ? m : ck;

  unsigned ksel = (ck & 4) ? __float_as_uint(tb[46]) : __float_as_uint(tb[45]);
  int kenc = (int)((ksel >> ((ck & 3) << 3)) & 0xFFu);

  bool r2 = (cm > gb) || ((cm == gb) && (kenc > gk));
  gb = r2 ? cm : gb;
  gk = r2 ? kenc : gk;
}

// R6: R5's LDS transport (VALUBusy 50->69, the proven win) at DOUBLE the
// occupancy: 1 block/thread -> 524288 threads -> 2048 WGs = 8 WG/CU = 8
// waves/SIMD (R5's 2-block layout capped the grid at 4 waves/SIMD; its
// residual 31% idle matches per-chunk lgkm exposure that more waves hide).
// launch_bounds(256,8) = 64-VGPR cap; 1-block live set fits (R3 variant: 24).
__global__ __launch_bounds__(256, 8) void _IQ2XSQuantWeight_12945031430379_kernel(
    const float* __restrict__ w, float* __restrict__ out, int nb) {
  __shared__ __align__(16) float lds_f[32 * 48];

  int tid = threadIdx.x;
  // one-time table stage: 1536 dwords / 256 threads = 6 each
#pragma unroll
  for (int j = 0; j < 6; ++j)
    lds_f[tid + 256 * j] = __uint_as_float(CT.v[tid + 256 * j]);
  __syncthreads();

  int t = blockIdx.x * blockDim.x + tid;
  if (t >= nb) return;

  const float4* wp = reinterpret_cast<const float4*>(w) + (size_t)2 * t;
  float4 w0 = wp[0];
  float4 w1 = wp[1];
  float wv[BLOCK] = {w0.x, w0.y, w0.z, w0.w, w1.x, w1.y, w1.z, w1.w};

  float a[BLOCK];
  unsigned sbits = 0u;
#pragma unroll
  for (int i = 0; i < BLOCK; ++i) {
    unsigned ub = __float_as_uint(wv[i]);
    sbits |= (ub >> 31) << i;
    a[i] = __uint_as_float(ub & 0x7fffffffu);  // == fabsf
  }

  float gb = -1.0f;
  int gk = 0;

#pragma unroll 1
  for (int c = 0; c < 32; ++c) {
    // 12 x ds_read_b128, wave-uniform address (broadcast, conflict-free)
    const float4* lt = reinterpret_cast<const float4*>(lds_f + c * 48);
    float4 t4[12];
#pragma unroll
    for (int q = 0; q < 12; ++q) t4[q] = lt[q];

    // static scatter to a named float[48] (all indices compile-time ->
    // SROA'd; the scheduler sinks loads toward uses, rolling window of regs)
    float tb[48];
#pragma unroll
    for (int q = 0; q < 12; ++q) {
      tb[4 * q + 0] = t4[q].x;
      tb[4 * q + 1] = t4[q].y;
      tb[4 * q + 2] = t4[q].z;
      tb[4 * q + 3] = t4[q].w;
    }

    chunk_step(tb, a, gb, gk);
  }

  // ---- epilogue: identical op sequence to R0..R5 (absmax 0.0078125) ----
  unsigned int bits = (unsigned int)GP.p[gk];  // divergent 1-byte gather, L1

  float q[BLOCK];
#pragma unroll
  for (int i = 0; i < BLOCK; ++i) q[i] = ((bits >> i) & 1u) ? 3.0f : 1.0f;

  float p[BLOCK];
#pragma unroll
  for (int i = 0; i < BLOCK; ++i) p[i] = a[i] * q[i];
  float num = ((p[0] + p[1]) + (p[2] + p[3])) + ((p[4] + p[5]) + (p[6] + p[7]));

  int popc = __popc(bits);
  float normf = (float)(8 + (popc << 3));
  float scale = num / normf;  // IEEE CR f32 divide (once)

  float o[BLOCK];
#pragma unroll
  for (int i = 0; i < BLOCK; ++i) {
    float wvi = __uint_as_float(__float_as_uint(a[i]) | (((sbits >> i) & 1u) << 31));
    float sg = (wvi > 0.0f) ? 1.0f : ((wvi < 0.0f) ? -1.0f : 0.0f);
    float deq = (scale * q[i]) * sg;
    o[i] = wvi + (deq - wvi);  // w + stop_gradient(deq - w)
  }

  float4 o0 = {o[0], o[1], o[2], o[3]};
  float4 o1 = {o[4], o[5], o[6], o[7]};
  float4* op = reinterpret_cast<float4*>(out) + (size_t)2 * t;
  op[0] = o0;
  op[1] = o1;
}

extern "C" void kernel_launch(void* const* d_in, const int* in_sizes, int n_in,
                              void* d_out, int out_size, void* d_ws, size_t ws_size,
                              hipStream_t stream) {
  (void)n_in; (void)d_ws; (void)ws_size; (void)out_size;
  const float* w = (const float*)d_in[0];
  float* out = (float*)d_out;
  int n = in_sizes[0];
  int nb = n / BLOCK;      // 524288 blocks, 1 per thread
  int threads = 256;
  int blocks = (nb + threads - 1) / threads;
  _IQ2XSQuantWeight_12945031430379_kernel<<<blocks, threads, 0, stream>>>(w, out, nb);
}

// Round 7
// 87.927 us; speedup vs baseline: 1.2573x; 1.2573x over previous
//
#include <hip/hip_runtime.h>

#define BLOCK 8
#define NGRID 512

// ---------------------------------------------------------------------------
// Compile-time replication of
//   np.random.RandomState(0).choice(np.array([1.0,3.0],f32), size=(512,8))
// (MT19937 legacy scalar seeding, one 32-bit draw per value, value = draw&1).
// Bit i of pattern byte = element i: g[i] = bit ? 3.0f : 1.0f.
// Dedup (first occurrence) is argmax-neutral. kenc = 255 - dedup_index, so
// "ties -> max kenc" == numpy first-max. Scan order = bit-reversed ascending
// (maximizes shared low-bit spine prefixes); selection is order-independent.
// ---------------------------------------------------------------------------
struct Sched {
  int nd;                      // distinct patterns (222)
  unsigned char kpat[256];     // kenc -> pattern byte (epilogue gather)
  unsigned char dfs_pat[256];  // scan ordinal -> pattern byte
  unsigned char dfs_ken[256];  // scan ordinal -> kenc
  unsigned char lowbit[256];   // ordinal -> lowest differing bit vs prev (0 for j=0)
  unsigned char csn[32];       // chunk -> member count (chunks of 8)
  unsigned char cslot[32][8];  // chunk, i -> slot (ordinal & 7), kenc-ascending
  unsigned char cken[32][8];   // chunk, i -> kenc,                kenc-ascending
};

constexpr unsigned char bitrev8c(unsigned v) {
  unsigned r = 0;
  for (int i = 0; i < 8; ++i) r |= ((v >> i) & 1u) << (7 - i);
  return (unsigned char)r;
}
constexpr int popcount8c(int v) {
  int p = 0;
  for (int i = 0; i < 8; ++i) p += (v >> i) & 1;
  return p;
}
constexpr int ctz8c(int v) {
  for (int i = 0; i < 8; ++i) if ((v >> i) & 1) return i;
  return 0;
}

constexpr Sched make_sched() {
  Sched t{};
  bool exists[256] = {};
  unsigned char kenc[256] = {};
  // --- MT19937, numpy legacy scalar seed 0 ---
  unsigned mt[624] = {};
  {
    unsigned s = 0u;
    for (int i = 0; i < 624; ++i) {
      mt[i] = s;
      s = 1812433253u * (s ^ (s >> 30)) + (unsigned)(i + 1);
    }
  }
  int pos = 624;
  int nd = 0;
  for (int j = 0; j < NGRID; ++j) {
    unsigned char b = 0;
    for (int i = 0; i < BLOCK; ++i) {
      if (pos == 624) {
        for (int k = 0; k < 624; ++k) {
          int k1 = (k + 1 < 624) ? k + 1 : 0;
          int k397 = (k + 397 < 624) ? k + 397 : k + 397 - 624;
          unsigned y = (mt[k] & 0x80000000u) | (mt[k1] & 0x7fffffffu);
          unsigned v = mt[k397] ^ (y >> 1);
          if (y & 1u) v ^= 0x9908b0dfu;
          mt[k] = v;
        }
        pos = 0;
      }
      unsigned y = mt[pos++];
      y ^= y >> 11;
      y ^= (y << 7) & 0x9d2c5680u;
      y ^= (y << 15) & 0xefc60000u;
      y ^= y >> 18;
      if (y & 1u) b |= (unsigned char)(1u << i);
    }
    if (!exists[b]) {
      exists[b] = true;
      kenc[b] = (unsigned char)(255 - nd);
      t.kpat[255 - nd] = b;
      ++nd;
    }
  }
  t.nd = nd;
  // --- scan order: bit-reversed ascending ---
  int m = 0;
  for (int r = 0; r < 256; ++r) {
    unsigned char b = bitrev8c((unsigned)r);
    if (exists[b]) {
      t.dfs_pat[m] = b;
      t.dfs_ken[m] = kenc[b];
      ++m;
    }
  }
  t.lowbit[0] = 0;
  for (int j = 1; j < nd; ++j)
    t.lowbit[j] = (unsigned char)ctz8c(t.dfs_pat[j] ^ t.dfs_pat[j - 1]);
  // --- chunks of 8, members sorted by kenc ascending (insertion sort) ---
  int nc = (nd + 7) / 8;
  for (int c = 0; c < nc; ++c) {
    int n = nd - 8 * c; if (n > 8) n = 8;
    t.csn[c] = (unsigned char)n;
    unsigned char sl[8] = {}, ke[8] = {};
    for (int i = 0; i < n; ++i) { sl[i] = (unsigned char)i; ke[i] = t.dfs_ken[8 * c + i]; }
    for (int i = 1; i < n; ++i) {
      unsigned char ks = ke[i], ss = sl[i];
      int p = i - 1;
      while (p >= 0 && ke[p] > ks) { ke[p + 1] = ke[p]; sl[p + 1] = sl[p]; --p; }
      ke[p + 1] = ks; sl[p + 1] = ss;
    }
    for (int i = 0; i < n; ++i) { t.cslot[c][i] = sl[i]; t.cken[c][i] = ke[i]; }
  }
  return t;
}

constexpr Sched SC = make_sched();
constexpr int ND = SC.nd;
static_assert(ND > 168 && ND <= 224, "section layout assumes 22..28 chunks");

// chunk-local winner index -> kenc, packed 8 bytes into a u64 (compile time)
constexpr unsigned long long pack_klut(int c) {
  unsigned long long v = 0ull;
  for (int i = 0; i < 8; ++i)
    v |= (unsigned long long)SC.cken[c][i] << (8 * i);
  return v;
}

// epilogue gather table: kenc -> pattern byte (L1-resident)
__device__ __constant__ const unsigned char g_pat[256] = {
#define P1(z) SC.kpat[z]
#define P8(z) P1(z), P1(z+1), P1(z+2), P1(z+3), P1(z+4), P1(z+5), P1(z+6), P1(z+7)
#define P64(z) P8(z), P8(z+8), P8(z+16), P8(z+24), P8(z+32), P8(z+40), P8(z+48), P8(z+56)
    P64(0), P64(64), P64(128), P64(192)
#undef P64
#undef P8
#undef P1
};

// ---------------------------------------------------------------------------
// Sectioned trie scan step (proven R0 body, bounded to [J0, JEND)).
// Chain values are scan-path-independent: recomputing all 8 spine levels at
// a section start (p0=0 at J==J0) yields bit-identical leaf d values, hence
// bit-identical scores (exact pow2 scale or Markstein CR division).
// Sections are chunk-aligned (J0 % 8 == 0), so chunk-close logic is global.
// ---------------------------------------------------------------------------
template <int J, int J0, int JEND>
struct Step {
  static __device__ __forceinline__ void run(const float (&a)[BLOCK], float (&sp)[9],
                                             float (&scs)[8], float &gb, int &gk) {
    constexpr int pat = SC.dfs_pat[J];
    constexpr int p0 = (J == J0) ? 0 : SC.lowbit[J];
#pragma unroll
    for (int l = 0; l < 8; ++l) {
      if (l >= p0) {
        if ((pat >> l) & 1)
          sp[l + 1] = __builtin_fmaf(a[l], 3.0f, sp[l]);
        else
          sp[l + 1] = sp[l] + a[l];
      }
    }
    float d = sp[8];
    float dd = d * d;
    constexpr int pc = popcount8c(pat);
    float sc;
    if constexpr (pc == 0)      sc = dd * 0.125f;      // /8   exact
    else if constexpr (pc == 1) sc = dd * 0.0625f;     // /16  exact
    else if constexpr (pc == 3) sc = dd * 0.03125f;    // /32  exact
    else if constexpr (pc == 7) sc = dd * 0.015625f;   // /64  exact
    else {
      constexpr float nf = (float)(8 * (1 + pc));
      constexpr float rcf = 1.0f / nf;                 // RN reciprocal (compile time)
      float q0 = dd * rcf;
      float r = __builtin_fmaf(-nf, q0, dd);           // exact residual
      sc = __builtin_fmaf(r, rcf, q0);                 // Markstein: == fl32(dd/nf)
    }
    scs[J & 7] = sc;

    if constexpr (((J & 7) == 7) || (J == ND - 1)) {
      constexpr int c = J >> 3;
      constexpr int n = SC.csn[c];
      float cm;
      if constexpr (n == 8) {
        cm = __builtin_fmaxf(
            __builtin_fmaxf(__builtin_fmaxf(scs[0], scs[1]), __builtin_fmaxf(scs[2], scs[3])),
            __builtin_fmaxf(__builtin_fmaxf(scs[4], scs[5]), __builtin_fmaxf(scs[6], scs[7])));
      } else {
        cm = scs[0];
#pragma unroll
        for (int i = 1; i < n; ++i) cm = __builtin_fmaxf(cm, scs[i]);
      }
      int ck = 0;
#pragma unroll
      for (int i = 0; i < n; ++i)   // kenc ascending: last write = min original k
        ck = (scs[SC.cslot[c][i]] == cm) ? i : ck;     // i is an inline constant
      constexpr unsigned long long klut = pack_klut(c);
      int kenc = (int)((unsigned)(klut >> (ck << 3)) & 0xFFu);
      bool r = (cm > gb) || ((cm == gb) && (kenc > gk));
      gb = r ? cm : gb;
      gk = r ? kenc : gk;
    }
    if constexpr (J + 1 < JEND) Step<J + 1, J0, JEND>::run(a, sp, scs, gb, gk);
  }
};

#define SETS_PER_WG 4

// ---------------------------------------------------------------------------
// R7: wave-sectioned trie. WG = 256 threads = 4 waves; per set, 64 blocks are
// staged in LDS; wave w straight-line-scans its chunk-aligned trie section
// (sections: w0 -> chunks 21..27 [54 leaves, shortest: w0 also runs the
// epilogue], w1 -> 0..6, w2 -> 7..13, w3 -> 14..20). Each wave LOOPS its
// ~4KB section over SETS_PER_WG sets -> I$-resident after pass 1, while
// total instruction count stays at the trie minimum (~2.2k/block).
// Cross-wave argmax via LDS (score,kenc) partials; the lexicographic rule
// (score desc, kenc desc) is associative and kenc is a GLOBAL priority, so
// the merged result == the sequential R0 scan (exact numpy min-k ties).
// 8 WGs/CU co-resident (5KB LDS, <=64 VGPR) absorb barrier bubbles.
// ---------------------------------------------------------------------------
__global__ __launch_bounds__(256, 8) void _IQ2XSQuantWeight_12945031430379_kernel(
    const float* __restrict__ w, float* __restrict__ out, int nsets) {
  __shared__ float lds_w[64 * 9];          // raw w, 64 blocks x 8 (+1 pad)
  __shared__ unsigned lds_part[4 * 64 * 2];  // per-wave (score bits, kenc)

  const int tid = threadIdx.x;
  const int lane = tid & 63;
  const int wid = tid >> 6;
  const int setBase = blockIdx.x * SETS_PER_WG;

  const uint2* gw = reinterpret_cast<const uint2*>(w);

  // prologue: stage set 0 into registers (coalesced 8B/lane)
  uint2 sreg = {0u, 0u};
  if (setBase < nsets) sreg = gw[(size_t)setBase * 256 + tid];

  for (int s = 0; s < SETS_PER_WG; ++s) {
    if (setBase + s >= nsets) break;  // WG-uniform

    // registers -> LDS (thread t: block t/4, elems (t&3)*2 .. +1)
    {
      int blk = tid >> 2, e = (tid & 3) * 2;
      lds_w[blk * 9 + e]     = __uint_as_float(sreg.x);
      lds_w[blk * 9 + e + 1] = __uint_as_float(sreg.y);
    }
    __syncthreads();

    // async-stage: issue next set's global loads now; consumed after the
    // epilogue barrier (latency hidden under the full scan phase).
    if (s + 1 < SETS_PER_WG && setBase + s + 1 < nsets)
      sreg = gw[(size_t)(setBase + s + 1) * 256 + tid];

    // ---- scan phase: wave 'wid' scans its section for block 'lane' ----
    float a[BLOCK];
#pragma unroll
    for (int i = 0; i < BLOCK; ++i)
      a[i] = __uint_as_float(__float_as_uint(lds_w[lane * 9 + i]) & 0x7fffffffu);
    // stride-9 ds_read_b32: bank = (9*lane+i)%32, 9 odd -> conflict-free

    float sp[9];
    sp[0] = 0.0f;
    float scs[8];
    float gb = -1.0f;
    int gk = 0;
    // wave-uniform dispatch (no lane divergence)
    if (wid == 0)      Step<168, 168, ND>::run(a, sp, scs, gb, gk);
    else if (wid == 1) Step<0,   0,   56>::run(a, sp, scs, gb, gk);
    else if (wid == 2) Step<56,  56,  112>::run(a, sp, scs, gb, gk);
    else               Step<112, 112, 168>::run(a, sp, scs, gb, gk);

    // publish partial (scores >= -0.0, so f32 max == bit-compare not needed;
    // we store raw bits and reduce in float)
    lds_part[(wid * 64 + lane) * 2]     = __float_as_uint(gb);
    lds_part[(wid * 64 + lane) * 2 + 1] = (unsigned)gk;
    __syncthreads();

    // ---- merge + epilogue: wave 0 only (issue-optimal; other waves wait
    // at the barrier and co-resident WGs fill the SIMD slots) ----
    if (wid == 0) {
      float best = __uint_as_float(lds_part[lane * 2]);
      int bk = (int)lds_part[lane * 2 + 1];
#pragma unroll
      for (int p = 1; p < 4; ++p) {
        float c = __uint_as_float(lds_part[(p * 64 + lane) * 2]);
        int ck = (int)lds_part[(p * 64 + lane) * 2 + 1];
        bool r = (c > best) || ((c == best) && (ck > bk));
        best = r ? c : best;
        bk = r ? ck : bk;
      }

      // epilogue: op-for-op the proven R0..R6 sequence (absmax 0.0078125),
      // on bit-identical raw w re-read from LDS.
      unsigned bits = (unsigned)g_pat[bk];

      float wv[BLOCK], av[BLOCK];
#pragma unroll
      for (int i = 0; i < BLOCK; ++i) {
        wv[i] = lds_w[lane * 9 + i];
        av[i] = __uint_as_float(__float_as_uint(wv[i]) & 0x7fffffffu);
      }

      float q[BLOCK];
#pragma unroll
      for (int i = 0; i < BLOCK; ++i) q[i] = ((bits >> i) & 1u) ? 3.0f : 1.0f;

      float p[BLOCK];
#pragma unroll
      for (int i = 0; i < BLOCK; ++i) p[i] = av[i] * q[i];
      float num = ((p[0] + p[1]) + (p[2] + p[3])) + ((p[4] + p[5]) + (p[6] + p[7]));

      int popc = __popc(bits);
      float normf = (float)(8 + (popc << 3));
      float scale = num / normf;  // IEEE CR f32 divide (once)

      float o[BLOCK];
#pragma unroll
      for (int i = 0; i < BLOCK; ++i) {
        float sg = (wv[i] > 0.0f) ? 1.0f : ((wv[i] < 0.0f) ? -1.0f : 0.0f);
        float deq = (scale * q[i]) * sg;
        o[i] = wv[i] + (deq - wv[i]);  // w + stop_gradient(deq - w)
      }

      float4 o0 = {o[0], o[1], o[2], o[3]};
      float4 o1 = {o[4], o[5], o[6], o[7]};
      float4* op = reinterpret_cast<float4*>(out) +
                   ((size_t)(setBase + s) * 64 + lane) * 2;
      op[0] = o0;
      op[1] = o1;
    }
    __syncthreads();  // protect lds_w/lds_part before next set's overwrite
  }
}

extern "C" void kernel_launch(void* const* d_in, const int* in_sizes, int n_in,
                              void* d_out, int out_size, void* d_ws, size_t ws_size,
                              hipStream_t stream) {
  (void)n_in; (void)d_ws; (void)ws_size; (void)out_size;
  const float* w = (const float*)d_in[0];
  float* out = (float*)d_out;
  int n = in_sizes[0];
  int nsets = n / 512;  // 64 blocks x 8 elems per set (4.19M -> 8192 sets)
  int blocks = (nsets + SETS_PER_WG - 1) / SETS_PER_WG;
  _IQ2XSQuantWeight_12945031430379_kernel<<<blocks, 256, 0, stream>>>(w, out, nsets);
}